// Round 5
// baseline (233.686 us; speedup 1.0000x reference)
//
#include <hip/hip_runtime.h>
#include <hip/hip_bf16.h>

constexpr int Bt  = 131072;
constexpr int OBS = 194;
constexpr int NT  = 128;   // 2 waves / block
constexpr int MT  = 32;    // rows per block (16 per wave)
constexpr int RS  = 72;    // h row stride (shorts): 144B rows -> 16B aligned, staggered banks
constexpr int LS  = 18;    // logit buffer row stride

// d_ws layout (shorts): B-fragment layouts for mfma_f32_16x16x32_bf16.
// frag_base[(kb*NTILES + nt)*64 + lane], 8 shorts each.
// fW1/fWc1: k = kb*32+(l>>4)*8+j; k<194 -> W[k][n]; k==194 -> bias[n]; else 0.
// fW2/fWc2/fWh: k-index permuted by gamma(s) = (s&3)*16 + (s>>2) to match the
// packed LDS layout of h/feat (bijection over 0..63 -> dot product unchanged).
constexpr int W1B_OFF  = 0;       // 7*4*64*8 = 28672
constexpr int WC1B_OFF = 28672;
constexpr int W2B_OFF  = 57344;   // 2*4*64*8 = 8192
constexpr int WC2B_OFF = 65536;
constexpr int WHB_OFF  = 73728;   // 2*1*64*8 = 1024 (cols 0-14: Wh, col 15: Wc3)

typedef short bf8   __attribute__((ext_vector_type(8)));
typedef float f32x4 __attribute__((ext_vector_type(4)));
typedef unsigned int u32;

__device__ __forceinline__ short f2bs(float f) {
    union { __hip_bfloat16 h; short s; } u;
    u.h = __float2bfloat16(f);
    return u.s;
}
__device__ __forceinline__ float bs2f(short s) {
    union { short s; __hip_bfloat16 h; } u;
    u.s = s;
    return __bfloat162float(u.h);
}
__device__ __forceinline__ u32 pk2(float a, float b) {
    union { __hip_bfloat162 h; u32 u; } r;
    r.h = __float22bfloat162_rn(float2{a, b});
    return r.u;
}
__device__ __forceinline__ float fast_tanh(float v) {
    v = fminf(fmaxf(v, -15.f), 15.f);
    float e = __expf(2.f * v);
    return (e - 1.f) * __builtin_amdgcn_rcpf(e + 1.f);
}

// ---------------- prep: weights -> B-fragment layout in d_ws ----------------
__global__ void __launch_bounds__(256) prep(
    const float* __restrict__ W1, const float* __restrict__ b1,
    const float* __restrict__ W2, const float* __restrict__ Wh,
    const float* __restrict__ Wc1, const float* __restrict__ bc1,
    const float* __restrict__ Wc2, const float* __restrict__ Wc3,
    short* __restrict__ ws)
{
    const int gid = blockIdx.x * 256 + threadIdx.x;
    const int gsz = gridDim.x * 256;

    for (int i = gid; i < 28672; i += gsz) {
        int j = i & 7, l = (i >> 3) & 63, nt = (i >> 9) & 3, kb = i >> 11;
        int k = kb * 32 + ((l >> 4) << 3) + j;
        int n = nt * 16 + (l & 15);
        short v1 = 0, v2 = 0;
        if (k < OBS) {
            v1 = f2bs(W1[k * 64 + n]);
            v2 = f2bs(Wc1[k * 64 + n]);
        } else if (k == OBS) {              // bias row, paired with A==1.0
            v1 = f2bs(b1[n]);
            v2 = f2bs(bc1[n]);
        }
        ws[W1B_OFF + i]  = v1;
        ws[WC1B_OFF + i] = v2;
    }
    for (int i = gid; i < 8192; i += gsz) {
        int j = i & 7, l = (i >> 3) & 63, nt = (i >> 9) & 3, kb = i >> 11;
        int s = kb * 32 + ((l >> 4) << 3) + j;
        int kp = (s & 3) * 16 + (s >> 2);   // gamma(s)
        int n = nt * 16 + (l & 15);
        ws[W2B_OFF + i]  = f2bs(W2[kp * 64 + n]);
        ws[WC2B_OFF + i] = f2bs(Wc2[kp * 64 + n]);
    }
    for (int i = gid; i < 1024; i += gsz) {
        int j = i & 7, l = (i >> 3) & 63, kb = i >> 9;
        int s = kb * 32 + ((l >> 4) << 3) + j;
        int kp = (s & 3) * 16 + (s >> 2);
        int cc = l & 15;
        float v;
        if (cc == 15) v = Wc3[kp];
        else { int e = cc / 5, a = cc - 5 * e; v = Wh[(e * 64 + kp) * 5 + a]; }
        ws[WHB_OFF + i] = f2bs(v);
    }
}

// ------------- main fused kernel: no barriers, biases folded into MFMA -------------
__global__ void __launch_bounds__(NT, 7) fused_ac(
    const float* __restrict__ x, const int* __restrict__ act_in,
    const float* __restrict__ b2, const float* __restrict__ bc2,
    const float* __restrict__ bh, const float* __restrict__ bc3,
    const short* __restrict__ ws,
    float* __restrict__ out)
{
    __shared__ __align__(16) short hA[2][16 * RS];   // 4608 B actor h/feat (packed cols)
    __shared__ __align__(16) short hC[2][16 * RS];   // 4608 B critic
    __shared__ short logitb[2][16 * LS];             // 1152 B
    __shared__ float valb[2][16];                    //  128 B
    // total 10496 B -> LDS allows 15 blocks/CU; launch_bounds(128,7) -> 14 blocks, 28 waves/CU

    const int t  = threadIdx.x;
    const int w  = t >> 6;
    const int l  = t & 63;
    const int q  = l >> 4;
    const int c  = l & 15;
    const int gm = blockIdx.x * MT + w * 16 + c;     // row this lane serves (A m-index = c)

    const bf8* __restrict__ fW1  = reinterpret_cast<const bf8*>(ws + W1B_OFF);
    const bf8* __restrict__ fWc1 = reinterpret_cast<const bf8*>(ws + WC1B_OFF);
    const bf8* __restrict__ fW2  = reinterpret_cast<const bf8*>(ws + W2B_OFF);
    const bf8* __restrict__ fWc2 = reinterpret_cast<const bf8*>(ws + WC2B_OFF);
    const bf8* __restrict__ fWh  = reinterpret_cast<const bf8*>(ws + WHB_OFF);

    // -------- prefetches (all issue up front, overlap the x-load latency) --------
    float b2v[4], bc2v[4];
    #pragma unroll
    for (int nt = 0; nt < 4; ++nt) {
        b2v[nt]  = b2[nt * 16 + c];
        bc2v[nt] = bc2[nt * 16 + c];
    }
    float bhv = (c < 15) ? bh[c] : bc3[0];           // head-bias / value-bias by column
    int act = 0;
    if (l < 16) act = act_in[gm];

    // ---------------- layer 1 (actor + critic share each x fragment) ----------------
    f32x4 aa[4], ac[4];
    #pragma unroll
    for (int nt = 0; nt < 4; ++nt) {
        aa[nt] = f32x4{0.f, 0.f, 0.f, 0.f};
        ac[nt] = f32x4{0.f, 0.f, 0.f, 0.f};
    }
    int ev = 0;
    {
        const float* xr = x + (size_t)gm * OBS;
        #pragma unroll
        for (int kb = 0; kb < 6; ++kb) {
            const float2* p = reinterpret_cast<const float2*>(xr + kb * 32 + q * 8);
            float2 v0 = p[0], v1 = p[1], v2 = p[2], v3 = p[3];
            if (kb == 0 && q == 0) {                 // argmax(x[0..2]) from registers
                float best = v0.x;
                if (v0.y > best) { best = v0.y; ev = 1; }
                if (v1.x > best) { ev = 2; }
            }
            union { bf8 v; u32 u[4]; } a;
            a.u[0] = pk2(v0.x, v0.y); a.u[1] = pk2(v1.x, v1.y);
            a.u[2] = pk2(v2.x, v2.y); a.u[3] = pk2(v3.x, v3.y);
            #pragma unroll
            for (int nt = 0; nt < 4; ++nt) {
                aa[nt] = __builtin_amdgcn_mfma_f32_16x16x32_bf16(a.v, fW1 [(kb * 4 + nt) * 64 + l], aa[nt], 0, 0, 0);
                ac[nt] = __builtin_amdgcn_mfma_f32_16x16x32_bf16(a.v, fWc1[(kb * 4 + nt) * 64 + l], ac[nt], 0, 0, 0);
            }
        }
        // kb=6: k=192,193 data; k=194 constant 1.0 (multiplies bias row of B)
        union { bf8 v; u32 u[4]; } a;
        a.u[0] = 0; a.u[1] = 0; a.u[2] = 0; a.u[3] = 0;
        if (q == 0) {
            float2 v = *reinterpret_cast<const float2*>(xr + 192);
            a.u[0] = pk2(v.x, v.y);
            a.u[1] = pk2(1.0f, 0.0f);
        }
        #pragma unroll
        for (int nt = 0; nt < 4; ++nt) {
            aa[nt] = __builtin_amdgcn_mfma_f32_16x16x32_bf16(a.v, fW1 [(6 * 4 + nt) * 64 + l], aa[nt], 0, 0, 0);
            ac[nt] = __builtin_amdgcn_mfma_f32_16x16x32_bf16(a.v, fWc1[(6 * 4 + nt) * 64 + l], ac[nt], 0, 0, 0);
        }
    }

    short* ha = hA[w];
    short* hc = hC[w];

    // tanh -> packed LDS write: row q*4+r, slots 4c..4c+3 hold cols {nt*16+c}
    #pragma unroll
    for (int r = 0; r < 4; ++r) {
        uint2 pa, pc;
        pa.x = pk2(fast_tanh(aa[0][r]), fast_tanh(aa[1][r]));
        pa.y = pk2(fast_tanh(aa[2][r]), fast_tanh(aa[3][r]));
        pc.x = pk2(fast_tanh(ac[0][r]), fast_tanh(ac[1][r]));
        pc.y = pk2(fast_tanh(ac[2][r]), fast_tanh(ac[3][r]));
        *reinterpret_cast<uint2*>(&ha[(q * 4 + r) * RS + 4 * c]) = pa;
        *reinterpret_cast<uint2*>(&hc[(q * 4 + r) * RS + 4 * c]) = pc;
    }

    // ---------------- layer 2 (bias via accumulator init; k gamma-permuted) ----------------
    #pragma unroll
    for (int nt = 0; nt < 4; ++nt) {
        aa[nt] = f32x4{b2v[nt], b2v[nt], b2v[nt], b2v[nt]};
        ac[nt] = f32x4{bc2v[nt], bc2v[nt], bc2v[nt], bc2v[nt]};
    }
    #pragma unroll
    for (int kb = 0; kb < 2; ++kb) {
        bf8 xa = *reinterpret_cast<const bf8*>(&ha[c * RS + kb * 32 + q * 8]);
        bf8 xc = *reinterpret_cast<const bf8*>(&hc[c * RS + kb * 32 + q * 8]);
        #pragma unroll
        for (int nt = 0; nt < 4; ++nt) {
            aa[nt] = __builtin_amdgcn_mfma_f32_16x16x32_bf16(xa, fW2 [(kb * 4 + nt) * 64 + l], aa[nt], 0, 0, 0);
            ac[nt] = __builtin_amdgcn_mfma_f32_16x16x32_bf16(xc, fWc2[(kb * 4 + nt) * 64 + l], ac[nt], 0, 0, 0);
        }
    }
    #pragma unroll
    for (int r = 0; r < 4; ++r) {
        uint2 pa, pc;
        pa.x = pk2(fast_tanh(aa[0][r]), fast_tanh(aa[1][r]));
        pa.y = pk2(fast_tanh(aa[2][r]), fast_tanh(aa[3][r]));
        pc.x = pk2(fast_tanh(ac[0][r]), fast_tanh(ac[1][r]));
        pc.y = pk2(fast_tanh(ac[2][r]), fast_tanh(ac[3][r]));
        *reinterpret_cast<uint2*>(&ha[(q * 4 + r) * RS + 4 * c]) = pa;
        *reinterpret_cast<uint2*>(&hc[(q * 4 + r) * RS + 4 * c]) = pc;
    }

    // -------- head: feat[16x64] @ WhB[64x16]; bh/bc3 folded into accumulator --------
    {
        f32x4 lg = f32x4{bhv, bhv, bhv, bhv};
        f32x4 vv = f32x4{bhv, bhv, bhv, bhv};
        #pragma unroll
        for (int kb = 0; kb < 2; ++kb) {
            bf8 bw = fWh[kb * 64 + l];
            bf8 fa = *reinterpret_cast<const bf8*>(&ha[c * RS + kb * 32 + q * 8]);
            bf8 fc = *reinterpret_cast<const bf8*>(&hc[c * RS + kb * 32 + q * 8]);
            lg = __builtin_amdgcn_mfma_f32_16x16x32_bf16(fa, bw, lg, 0, 0, 0);
            vv = __builtin_amdgcn_mfma_f32_16x16x32_bf16(fc, bw, vv, 0, 0, 0);
        }
        short* lw = logitb[w];
        #pragma unroll
        for (int r = 0; r < 4; ++r)
            lw[(q * 4 + r) * LS + c] = f2bs(lg[r]);
        if (c == 15) {
            #pragma unroll
            for (int r = 0; r < 4; ++r)
                valb[w][q * 4 + r] = vv[r];
        }
    }

    // ---------------- epilogue: q==0 lanes only, no global reads ----------------
    if (l < 16) {
        const short* lw = logitb[w];
        float lg[5];
        #pragma unroll
        for (int a = 0; a < 5; ++a)
            lg[a] = bs2f(lw[c * LS + ev * 5 + a]);
        float mx = lg[0];
        #pragma unroll
        for (int a = 1; a < 5; ++a) mx = fmaxf(mx, lg[a]);
        float se = 0.f;
        #pragma unroll
        for (int a = 0; a < 5; ++a) se += __expf(lg[a] - mx);
        float lse = __logf(se) + mx;
        float lsel = lg[0];
        #pragma unroll
        for (int a = 1; a < 5; ++a) lsel = (act == a) ? lg[a] : lsel;
        float ent = 0.f;
        #pragma unroll
        for (int a = 0; a < 5; ++a) { float lp = lg[a] - lse; ent -= __expf(lp) * lp; }

        out[gm]          = (float)act;
        out[Bt + gm]     = lsel - lse;
        out[2 * Bt + gm] = ent;
        out[3 * Bt + gm] = valb[w][c];
    }
}

extern "C" void kernel_launch(void* const* d_in, const int* in_sizes, int n_in,
                              void* d_out, int out_size, void* d_ws, size_t ws_size,
                              hipStream_t stream) {
    const float* x   = (const float*)d_in[0];
    const int*   act = (const int*)  d_in[1];
    const float* W1  = (const float*)d_in[2];
    const float* b1  = (const float*)d_in[3];
    const float* W2  = (const float*)d_in[4];
    const float* b2  = (const float*)d_in[5];
    const float* Wh  = (const float*)d_in[6];
    const float* bh  = (const float*)d_in[7];
    const float* Wc1 = (const float*)d_in[8];
    const float* bc1 = (const float*)d_in[9];
    const float* Wc2 = (const float*)d_in[10];
    const float* bc2 = (const float*)d_in[11];
    const float* Wc3 = (const float*)d_in[12];
    const float* bc3 = (const float*)d_in[13];
    float* out = (float*)d_out;
    short* ws  = (short*)d_ws;

    hipLaunchKernelGGL(prep, dim3(64), dim3(256), 0, stream,
                       W1, b1, W2, Wh, Wc1, bc1, Wc2, Wc3, ws);
    hipLaunchKernelGGL(fused_ac, dim3(Bt / MT), dim3(NT), 0, stream,
                       x, act, b2, bc2, bh, bc3, ws, out);
}

// Round 6
// 186.720 us; speedup vs baseline: 1.2515x; 1.2515x over previous
//
#include <hip/hip_runtime.h>
#include <hip/hip_bf16.h>

constexpr int Bt  = 131072;
constexpr int OBS = 194;
constexpr int NT  = 256;   // 4 waves / block
constexpr int MT  = 64;    // rows per block (16 per wave)
constexpr int RS  = 72;    // h row stride (shorts)
constexpr int LS  = 18;    // logit row stride (shorts)

// ---- d_ws layout (SHORT offsets). B-fragments for mfma_f32_16x16x32_bf16:
// frag idx (kb*4+nt)*64 + lane, 8 shorts each (16 B, lane-contiguous).
// fW1/fWc1: k<194 -> W[k][n]; k==194 -> bias[n] (A supplies 1.0); else 0.
// fW2/fWc2/fWh: k permuted by gamma(s) = (s&3)*16 + (s>>2) to match packed h.
constexpr int W1B_S  = 0;       // 14336 shorts (28672 B)
constexpr int WC1B_S = 14336;   // 14336
constexpr int W2B_S  = 28672;   // 8192  (16384 B)
constexpr int WC2B_S = 36864;   // 8192
constexpr int WHB_S  = 45056;   // 1024  (2048 B; cols 0-14 Wh, col 15 Wc3)
// stage1 = ws bytes [0, 57344) -> LDS [0, 57344)   (56 chunks of 1 KB)
// stage2 = ws bytes [57344, 92160) -> LDS [0, 34816) (34 chunks)

typedef short bf8   __attribute__((ext_vector_type(8)));
typedef float f32x4 __attribute__((ext_vector_type(4)));
typedef unsigned int u32;

__device__ __forceinline__ short f2bs(float f) {
    union { __hip_bfloat16 h; short s; } u;
    u.h = __float2bfloat16(f);
    return u.s;
}
__device__ __forceinline__ float bs2f(short s) {
    union { short s; __hip_bfloat16 h; } u;
    u.s = s;
    return __bfloat162float(u.h);
}
__device__ __forceinline__ u32 pk2(float a, float b) {
    union { __hip_bfloat162 h; u32 u; } r;
    r.h = __float22bfloat162_rn(float2{a, b});
    return r.u;
}
__device__ __forceinline__ float fast_tanh(float v) {
    v = fminf(fmaxf(v, -15.f), 15.f);
    float e = __expf(2.f * v);
    return (e - 1.f) * __builtin_amdgcn_rcpf(e + 1.f);
}
__device__ __forceinline__ void dma16(const void* g, void* s) {
    __builtin_amdgcn_global_load_lds(
        (const __attribute__((address_space(1))) u32*)g,
        (__attribute__((address_space(3))) u32*)s, 16, 0, 0);
}

// ---------------- prep: weights -> B-fragment layout in d_ws ----------------
__global__ void __launch_bounds__(256) prep(
    const float* __restrict__ W1, const float* __restrict__ b1,
    const float* __restrict__ W2, const float* __restrict__ Wh,
    const float* __restrict__ Wc1, const float* __restrict__ bc1,
    const float* __restrict__ Wc2, const float* __restrict__ Wc3,
    short* __restrict__ ws)
{
    const int gid = blockIdx.x * 256 + threadIdx.x;
    const int gsz = gridDim.x * 256;

    for (int i = gid; i < 14336; i += gsz) {
        int j = i & 7, l = (i >> 3) & 63, nt = (i >> 9) & 3, kb = i >> 11;
        int k = kb * 32 + ((l >> 4) << 3) + j;
        int n = nt * 16 + (l & 15);
        short v1 = 0, v2 = 0;
        if (k < OBS) {
            v1 = f2bs(W1[k * 64 + n]);
            v2 = f2bs(Wc1[k * 64 + n]);
        } else if (k == OBS) {              // bias row (A supplies 1.0)
            v1 = f2bs(b1[n]);
            v2 = f2bs(bc1[n]);
        }
        ws[W1B_S + i]  = v1;
        ws[WC1B_S + i] = v2;
    }
    for (int i = gid; i < 8192; i += gsz) {
        int j = i & 7, l = (i >> 3) & 63, nt = (i >> 9) & 3, kb = i >> 11;
        int s = kb * 32 + ((l >> 4) << 3) + j;
        int kp = (s & 3) * 16 + (s >> 2);   // gamma(s)
        int n = nt * 16 + (l & 15);
        ws[W2B_S + i]  = f2bs(W2[kp * 64 + n]);
        ws[WC2B_S + i] = f2bs(Wc2[kp * 64 + n]);
    }
    for (int i = gid; i < 1024; i += gsz) {
        int j = i & 7, l = (i >> 3) & 63, kb = i >> 9;
        int s = kb * 32 + ((l >> 4) << 3) + j;
        int kp = (s & 3) * 16 + (s >> 2);
        int cc = l & 15;
        float v;
        if (cc == 15) v = Wc3[kp];
        else { int e = cc / 5, a = cc - 5 * e; v = Wh[(e * 64 + kp) * 5 + a]; }
        ws[WHB_S + i] = f2bs(v);
    }
}

// -------- main: B-frags staged to LDS (DMA), region aliased across phases --------
__global__ void __launch_bounds__(NT, 2) fused_ac(
    const float* __restrict__ x, const int* __restrict__ act_in,
    const float* __restrict__ b2, const float* __restrict__ bc2,
    const float* __restrict__ bh, const float* __restrict__ bc3,
    const short* __restrict__ ws,
    float* __restrict__ out)
{
    // phase 1: [0,28672) W1 frags | [28672,57344) Wc1 frags
    // phase 2: [0,16384) W2 | [16384,32768) Wc2 | [32768,34816) Wh/Wc3
    //          [34816,44032) hA | [44032,53248) hC
    //          [53248,55552) logits | [55552,55808) value
    __shared__ __align__(16) char smem[57344];

    const int t  = threadIdx.x;
    const int w  = t >> 6;
    const int l  = t & 63;
    const int q  = l >> 4;
    const int c  = l & 15;
    const int gm = blockIdx.x * MT + w * 16 + c;

    // ---- stage 1 DMA: 56 chunks of 1 KB (both layer-1 weight sets) ----
    {
        const char* g = ((const char*)ws) + (size_t)(w * 14) * 1024 + l * 16;
        char* s = smem + (w * 14) * 1024 + l * 16;
        #pragma unroll
        for (int i = 0; i < 14; ++i)
            dma16(g + i * 1024, s + i * 1024);
    }

    // ---- prefetches + x load/pack (overlap DMA) ----
    float b2v[4], bc2v[4];
    #pragma unroll
    for (int nt = 0; nt < 4; ++nt) {
        b2v[nt]  = b2[nt * 16 + c];
        bc2v[nt] = bc2[nt * 16 + c];
    }
    float bhv = (c < 15) ? bh[c] : bc3[0];
    int act = 0;
    if (l < 16) act = act_in[gm];

    union AF { u32 u[4]; bf8 v; } af[7];
    int ev = 0;
    {
        const float* xr = x + (size_t)gm * OBS;
        #pragma unroll
        for (int kb = 0; kb < 6; ++kb) {
            const float2* p = reinterpret_cast<const float2*>(xr + kb * 32 + q * 8);
            float2 v0 = p[0], v1 = p[1], v2 = p[2], v3 = p[3];
            if (kb == 0 && q == 0) {             // argmax(x[0..2]) in registers
                float best = v0.x;
                if (v0.y > best) { best = v0.y; ev = 1; }
                if (v1.x > best) { ev = 2; }
            }
            af[kb].u[0] = pk2(v0.x, v0.y); af[kb].u[1] = pk2(v1.x, v1.y);
            af[kb].u[2] = pk2(v2.x, v2.y); af[kb].u[3] = pk2(v3.x, v3.y);
        }
        af[6].u[0] = 0; af[6].u[1] = 0; af[6].u[2] = 0; af[6].u[3] = 0;
        if (q == 0) {                            // k=192,193 data; k=194 -> 1.0 (bias)
            float2 v = *reinterpret_cast<const float2*>(xr + 192);
            af[6].u[0] = pk2(v.x, v.y);
            af[6].u[1] = pk2(1.0f, 0.0f);
        }
    }

    __syncthreads();                             // B1: stage-1 DMA complete

    // ---- layer 1: B from LDS (ds_read_b128), actor + critic ----
    const bf8* fW1L  = reinterpret_cast<const bf8*>(smem);
    const bf8* fWc1L = reinterpret_cast<const bf8*>(smem + 28672);
    f32x4 aa[4], ac[4];
    #pragma unroll
    for (int nt = 0; nt < 4; ++nt) {
        aa[nt] = f32x4{0.f, 0.f, 0.f, 0.f};
        ac[nt] = f32x4{0.f, 0.f, 0.f, 0.f};
    }
    #pragma unroll
    for (int kb = 0; kb < 7; ++kb) {
        bf8 a = af[kb].v;
        #pragma unroll
        for (int nt = 0; nt < 4; ++nt) {
            aa[nt] = __builtin_amdgcn_mfma_f32_16x16x32_bf16(a, fW1L [(kb * 4 + nt) * 64 + l], aa[nt], 0, 0, 0);
            ac[nt] = __builtin_amdgcn_mfma_f32_16x16x32_bf16(a, fWc1L[(kb * 4 + nt) * 64 + l], ac[nt], 0, 0, 0);
        }
    }
    // tanh in registers (bias was folded via k=194 row)
    #pragma unroll
    for (int nt = 0; nt < 4; ++nt)
        #pragma unroll
        for (int r = 0; r < 4; ++r) {
            aa[nt][r] = fast_tanh(aa[nt][r]);
            ac[nt][r] = fast_tanh(ac[nt][r]);
        }

    __syncthreads();                             // B2: all waves done reading W1/Wc1 LDS

    // ---- stage 2 DMA (layer-2/head frags into aliased region) + h writes ----
    {
        const char* g = ((const char*)ws) + 57344 + (size_t)(w * 9) * 1024 + l * 16;
        char* s = smem + (w * 9) * 1024 + l * 16;
        #pragma unroll
        for (int i = 0; i < 9; ++i)
            if (w * 9 + i < 34)
                dma16(g + i * 1024, s + i * 1024);
    }
    short* ha = reinterpret_cast<short*>(smem + 34816 + w * 2304);
    short* hc = reinterpret_cast<short*>(smem + 44032 + w * 2304);
    #pragma unroll
    for (int r = 0; r < 4; ++r) {                // packed cols: slot 4c+i = col i*16+c
        uint2 pa, pc;
        pa.x = pk2(aa[0][r], aa[1][r]); pa.y = pk2(aa[2][r], aa[3][r]);
        pc.x = pk2(ac[0][r], ac[1][r]); pc.y = pk2(ac[2][r], ac[3][r]);
        *reinterpret_cast<uint2*>(&ha[(q * 4 + r) * RS + 4 * c]) = pa;
        *reinterpret_cast<uint2*>(&hc[(q * 4 + r) * RS + 4 * c]) = pc;
    }

    __syncthreads();                             // B3: stage-2 DMA + h visible

    // ---- layer 2 (bias via acc init; k gamma-permuted to match packed h) ----
    const bf8* fW2L  = reinterpret_cast<const bf8*>(smem);
    const bf8* fWc2L = reinterpret_cast<const bf8*>(smem + 16384);
    const bf8* fWhL  = reinterpret_cast<const bf8*>(smem + 32768);
    #pragma unroll
    for (int nt = 0; nt < 4; ++nt) {
        aa[nt] = f32x4{b2v[nt], b2v[nt], b2v[nt], b2v[nt]};
        ac[nt] = f32x4{bc2v[nt], bc2v[nt], bc2v[nt], bc2v[nt]};
    }
    #pragma unroll
    for (int kb = 0; kb < 2; ++kb) {
        bf8 xa = *reinterpret_cast<const bf8*>(&ha[c * RS + kb * 32 + q * 8]);
        bf8 xc = *reinterpret_cast<const bf8*>(&hc[c * RS + kb * 32 + q * 8]);
        #pragma unroll
        for (int nt = 0; nt < 4; ++nt) {
            aa[nt] = __builtin_amdgcn_mfma_f32_16x16x32_bf16(xa, fW2L [(kb * 4 + nt) * 64 + l], aa[nt], 0, 0, 0);
            ac[nt] = __builtin_amdgcn_mfma_f32_16x16x32_bf16(xc, fWc2L[(kb * 4 + nt) * 64 + l], ac[nt], 0, 0, 0);
        }
    }
    #pragma unroll
    for (int r = 0; r < 4; ++r) {
        uint2 pa, pc;
        pa.x = pk2(fast_tanh(aa[0][r]), fast_tanh(aa[1][r]));
        pa.y = pk2(fast_tanh(aa[2][r]), fast_tanh(aa[3][r]));
        pc.x = pk2(fast_tanh(ac[0][r]), fast_tanh(ac[1][r]));
        pc.y = pk2(fast_tanh(ac[2][r]), fast_tanh(ac[3][r]));
        *reinterpret_cast<uint2*>(&ha[(q * 4 + r) * RS + 4 * c]) = pa;
        *reinterpret_cast<uint2*>(&hc[(q * 4 + r) * RS + 4 * c]) = pc;
    }

    // ---- head: feat[16x64] @ [64x16] (cols 0-14 logits, col 15 value) ----
    short* lw = reinterpret_cast<short*>(smem + 53248 + w * 576);
    float* vb = reinterpret_cast<float*>(smem + 55552 + w * 64);
    {
        f32x4 lg = f32x4{bhv, bhv, bhv, bhv};
        f32x4 vv = f32x4{bhv, bhv, bhv, bhv};
        #pragma unroll
        for (int kb = 0; kb < 2; ++kb) {
            bf8 bw = fWhL[kb * 64 + l];
            bf8 fa = *reinterpret_cast<const bf8*>(&ha[c * RS + kb * 32 + q * 8]);
            bf8 fc = *reinterpret_cast<const bf8*>(&hc[c * RS + kb * 32 + q * 8]);
            lg = __builtin_amdgcn_mfma_f32_16x16x32_bf16(fa, bw, lg, 0, 0, 0);
            vv = __builtin_amdgcn_mfma_f32_16x16x32_bf16(fc, bw, vv, 0, 0, 0);
        }
        #pragma unroll
        for (int r = 0; r < 4; ++r)
            lw[(q * 4 + r) * LS + c] = f2bs(lg[r]);
        if (c == 15) {
            #pragma unroll
            for (int r = 0; r < 4; ++r)
                vb[q * 4 + r] = vv[r];
        }
    }

    // ---- epilogue: lanes 0-15 (wave-local LDS, in-order DS pipe) ----
    if (l < 16) {
        float lg[5];
        #pragma unroll
        for (int a = 0; a < 5; ++a)
            lg[a] = bs2f(lw[c * LS + ev * 5 + a]);
        float mx = lg[0];
        #pragma unroll
        for (int a = 1; a < 5; ++a) mx = fmaxf(mx, lg[a]);
        float se = 0.f;
        #pragma unroll
        for (int a = 0; a < 5; ++a) se += __expf(lg[a] - mx);
        float lse = __logf(se) + mx;
        float lsel = lg[0];
        #pragma unroll
        for (int a = 1; a < 5; ++a) lsel = (act == a) ? lg[a] : lsel;
        float ent = 0.f;
        #pragma unroll
        for (int a = 0; a < 5; ++a) { float lp = lg[a] - lse; ent -= __expf(lp) * lp; }

        out[gm]          = (float)act;
        out[Bt + gm]     = lsel - lse;
        out[2 * Bt + gm] = ent;
        out[3 * Bt + gm] = vb[c];
    }
}

extern "C" void kernel_launch(void* const* d_in, const int* in_sizes, int n_in,
                              void* d_out, int out_size, void* d_ws, size_t ws_size,
                              hipStream_t stream) {
    const float* x   = (const float*)d_in[0];
    const int*   act = (const int*)  d_in[1];
    const float* W1  = (const float*)d_in[2];
    const float* b1  = (const float*)d_in[3];
    const float* W2  = (const float*)d_in[4];
    const float* b2  = (const float*)d_in[5];
    const float* Wh  = (const float*)d_in[6];
    const float* bh  = (const float*)d_in[7];
    const float* Wc1 = (const float*)d_in[8];
    const float* bc1 = (const float*)d_in[9];
    const float* Wc2 = (const float*)d_in[10];
    const float* bc2 = (const float*)d_in[11];
    const float* Wc3 = (const float*)d_in[12];
    const float* bc3 = (const float*)d_in[13];
    float* out = (float*)d_out;
    short* ws  = (short*)d_ws;

    hipLaunchKernelGGL(prep, dim3(32), dim3(256), 0, stream,
                       W1, b1, W2, Wh, Wc1, bc1, Wc2, Wc3, ws);
    hipLaunchKernelGGL(fused_ac, dim3(Bt / MT), dim3(NT), 0, stream,
                       x, act, b2, bc2, bh, bc3, ws, out);
}

// Round 7
// 183.068 us; speedup vs baseline: 1.2765x; 1.0199x over previous
//
#include <hip/hip_runtime.h>
#include <hip/hip_bf16.h>

constexpr int Bt    = 131072;
constexpr int OBS   = 194;
constexpr int NT    = 512;   // 8 waves / block (one block per CU)
constexpr int RPB   = 512;   // rows per block
constexpr int ITERS = 4;     // 128 rows per iteration (16 per wave)
constexpr int RS    = 72;    // h row stride (shorts)
constexpr int LS    = 18;    // logit row stride (shorts)

// ---- d_ws layout (SHORT offsets), byte-contiguous [0, 92160) for one DMA:
// B-fragments for mfma_f32_16x16x32_bf16: frag (kb*4+nt)*64 + lane, 8 shorts.
// fW1/fWc1: k<194 -> W[k][n]; k==194 -> bias[n] (A supplies 1.0); else 0.
// fW2/fWc2/fWh: k permuted by gamma(s) = (s&3)*16 + (s>>2) to match packed h.
constexpr int W1B_S  = 0;       // 14336 shorts -> bytes [0, 28672)
constexpr int WC1B_S = 14336;   // bytes [28672, 57344)
constexpr int W2B_S  = 28672;   // bytes [57344, 73728)
constexpr int WC2B_S = 36864;   // bytes [73728, 90112)
constexpr int WHB_S  = 45056;   // bytes [90112, 92160)  cols 0-14 Wh, col 15 Wc3

// ---- LDS layout (bytes) ----
constexpr int L_W1  = 0;
constexpr int L_WC1 = 28672;
constexpr int L_W2  = 57344;
constexpr int L_WC2 = 73728;
constexpr int L_WH  = 90112;
constexpr int L_HA  = 92160;    // + w*4608 (hA 2304 | hC 2304)
constexpr int L_LG  = 129024;   // + w*576
constexpr int L_VB  = 133632;   // + w*64
constexpr int L_TOT = 134144;   // < 160 KiB

typedef short bf8   __attribute__((ext_vector_type(8)));
typedef float f32x4 __attribute__((ext_vector_type(4)));
typedef unsigned int u32;

__device__ __forceinline__ short f2bs(float f) {
    union { __hip_bfloat16 h; short s; } u;
    u.h = __float2bfloat16(f);
    return u.s;
}
__device__ __forceinline__ float bs2f(short s) {
    union { short s; __hip_bfloat16 h; } u;
    u.s = s;
    return __bfloat162float(u.h);
}
__device__ __forceinline__ u32 pk2(float a, float b) {
    union { __hip_bfloat162 h; u32 u; } r;
    r.h = __float22bfloat162_rn(float2{a, b});
    return r.u;
}
__device__ __forceinline__ float fast_tanh(float v) {
    v = fminf(fmaxf(v, -15.f), 15.f);
    float e = __expf(2.f * v);
    return (e - 1.f) * __builtin_amdgcn_rcpf(e + 1.f);
}
__device__ __forceinline__ void dma16(const void* g, void* s) {
    __builtin_amdgcn_global_load_lds(
        (const __attribute__((address_space(1))) u32*)g,
        (__attribute__((address_space(3))) u32*)s, 16, 0, 0);
}

// ---------------- prep: weights -> B-fragment layout in d_ws ----------------
__global__ void __launch_bounds__(256) prep(
    const float* __restrict__ W1, const float* __restrict__ b1,
    const float* __restrict__ W2, const float* __restrict__ Wh,
    const float* __restrict__ Wc1, const float* __restrict__ bc1,
    const float* __restrict__ Wc2, const float* __restrict__ Wc3,
    short* __restrict__ ws)
{
    const int gid = blockIdx.x * 256 + threadIdx.x;
    const int gsz = gridDim.x * 256;

    for (int i = gid; i < 14336; i += gsz) {
        int j = i & 7, l = (i >> 3) & 63, nt = (i >> 9) & 3, kb = i >> 11;
        int k = kb * 32 + ((l >> 4) << 3) + j;
        int n = nt * 16 + (l & 15);
        short v1 = 0, v2 = 0;
        if (k < OBS) {
            v1 = f2bs(W1[k * 64 + n]);
            v2 = f2bs(Wc1[k * 64 + n]);
        } else if (k == OBS) {              // bias row (A supplies 1.0)
            v1 = f2bs(b1[n]);
            v2 = f2bs(bc1[n]);
        }
        ws[W1B_S + i]  = v1;
        ws[WC1B_S + i] = v2;
    }
    for (int i = gid; i < 8192; i += gsz) {
        int j = i & 7, l = (i >> 3) & 63, nt = (i >> 9) & 3, kb = i >> 11;
        int s = kb * 32 + ((l >> 4) << 3) + j;
        int kp = (s & 3) * 16 + (s >> 2);   // gamma(s)
        int n = nt * 16 + (l & 15);
        ws[W2B_S + i]  = f2bs(W2[kp * 64 + n]);
        ws[WC2B_S + i] = f2bs(Wc2[kp * 64 + n]);
    }
    for (int i = gid; i < 1024; i += gsz) {
        int j = i & 7, l = (i >> 3) & 63, kb = i >> 9;
        int s = kb * 32 + ((l >> 4) << 3) + j;
        int kp = (s & 3) * 16 + (s >> 2);
        int cc = l & 15;
        float v;
        if (cc == 15) v = Wc3[kp];
        else { int e = cc / 5, a = cc - 5 * e; v = Wh[(e * 64 + kp) * 5 + a]; }
        ws[WHB_S + i] = f2bs(v);
    }
}

// ------- main: persistent blocks, all weights LDS-resident, barrier-free loop -------
__global__ void __launch_bounds__(NT, 2) fused_ac(
    const float* __restrict__ x, const int* __restrict__ act_in,
    const float* __restrict__ b2, const float* __restrict__ bc2,
    const float* __restrict__ bh, const float* __restrict__ bc3,
    const short* __restrict__ ws,
    float* __restrict__ out)
{
    __shared__ __align__(16) char smem[L_TOT];

    const int t    = threadIdx.x;
    const int w    = t >> 6;
    const int l    = t & 63;
    const int q    = l >> 4;
    const int c    = l & 15;
    const int base = blockIdx.x * RPB;

    // ---- single DMA: all 92160 B of fragments (5760 16-B chunks) ----
    #pragma unroll
    for (int i = 0; i < 12; ++i) {
        int idx = i * NT + t;
        if (idx < 5760)
            dma16(((const char*)ws) + idx * 16, smem + idx * 16);
    }

    // ---- bias prefetch (overlaps DMA) ----
    float b2v[4], bc2v[4];
    #pragma unroll
    for (int nt = 0; nt < 4; ++nt) {
        b2v[nt]  = b2[nt * 16 + c];
        bc2v[nt] = bc2[nt * 16 + c];
    }
    float bhv = (c < 15) ? bh[c] : bc3[0];

    // ---- raw x buffer + pack machinery ----
    float2 raw[24]; float2 rt6;
    auto loadraw = [&](int gm2) {
        const float* xr = x + (size_t)gm2 * OBS;
        #pragma unroll
        for (int kb = 0; kb < 6; ++kb) {
            const float2* p = reinterpret_cast<const float2*>(xr + kb * 32 + q * 8);
            raw[kb * 4 + 0] = p[0]; raw[kb * 4 + 1] = p[1];
            raw[kb * 4 + 2] = p[2]; raw[kb * 4 + 3] = p[3];
        }
        rt6 = float2{0.f, 0.f};
        if (q == 0) rt6 = *reinterpret_cast<const float2*>(xr + 192);
    };
    union AF { u32 u[4]; bf8 v; } af[7];
    int ev = 0;
    auto packaf = [&]() {
        #pragma unroll
        for (int kb = 0; kb < 6; ++kb) {
            af[kb].u[0] = pk2(raw[kb * 4 + 0].x, raw[kb * 4 + 0].y);
            af[kb].u[1] = pk2(raw[kb * 4 + 1].x, raw[kb * 4 + 1].y);
            af[kb].u[2] = pk2(raw[kb * 4 + 2].x, raw[kb * 4 + 2].y);
            af[kb].u[3] = pk2(raw[kb * 4 + 3].x, raw[kb * 4 + 3].y);
        }
        af[6].u[0] = 0; af[6].u[1] = 0; af[6].u[2] = 0; af[6].u[3] = 0;
        if (q == 0) {                       // k=192,193 data; k=194 -> 1.0 (bias row)
            af[6].u[0] = pk2(rt6.x, rt6.y);
            af[6].u[1] = pk2(1.0f, 0.0f);
        }
        ev = 0;                             // argmax(x[0..2]) — valid for q==0 lanes
        float bbest = raw[0].x;
        if (raw[0].y > bbest) { bbest = raw[0].y; ev = 1; }
        if (raw[1].x > bbest) { ev = 2; }
    };

    loadraw(base + w * 16 + c);

    __syncthreads();                        // the ONLY barrier: weights + x0 resident

    packaf();

    const bf8* fW1L  = reinterpret_cast<const bf8*>(smem + L_W1);
    const bf8* fWc1L = reinterpret_cast<const bf8*>(smem + L_WC1);
    const bf8* fW2L  = reinterpret_cast<const bf8*>(smem + L_W2);
    const bf8* fWc2L = reinterpret_cast<const bf8*>(smem + L_WC2);
    const bf8* fWhL  = reinterpret_cast<const bf8*>(smem + L_WH);
    short* ha = reinterpret_cast<short*>(smem + L_HA + w * 4608);
    short* hc = ha + 2304 / 2;
    short* lw = reinterpret_cast<short*>(smem + L_LG + w * 576);
    float* vb = reinterpret_cast<float*>(smem + L_VB + w * 64);

    #pragma unroll 1
    for (int i = 0; i < ITERS; ++i) {
        const int gm = base + i * 128 + w * 16 + c;
        int act = 0;
        if (l < 16) act = act_in[gm];
        const int evc = ev;

        // prefetch next iteration's x (issues early; consumed at loop end)
        if (i + 1 < ITERS) loadraw(base + (i + 1) * 128 + w * 16 + c);

        // ---- layer 1: actor + critic (bias folded via k=194 row) ----
        f32x4 aa[4], ac[4];
        #pragma unroll
        for (int nt = 0; nt < 4; ++nt) {
            aa[nt] = f32x4{0.f, 0.f, 0.f, 0.f};
            ac[nt] = f32x4{0.f, 0.f, 0.f, 0.f};
        }
        #pragma unroll
        for (int kb = 0; kb < 7; ++kb) {
            bf8 a = af[kb].v;
            #pragma unroll
            for (int nt = 0; nt < 4; ++nt) {
                aa[nt] = __builtin_amdgcn_mfma_f32_16x16x32_bf16(a, fW1L [(kb * 4 + nt) * 64 + l], aa[nt], 0, 0, 0);
                ac[nt] = __builtin_amdgcn_mfma_f32_16x16x32_bf16(a, fWc1L[(kb * 4 + nt) * 64 + l], ac[nt], 0, 0, 0);
            }
        }
        // tanh -> packed wave-local LDS (slot 4c+i = col i*16+c; gamma on B side)
        #pragma unroll
        for (int r = 0; r < 4; ++r) {
            uint2 pa, pc;
            pa.x = pk2(fast_tanh(aa[0][r]), fast_tanh(aa[1][r]));
            pa.y = pk2(fast_tanh(aa[2][r]), fast_tanh(aa[3][r]));
            pc.x = pk2(fast_tanh(ac[0][r]), fast_tanh(ac[1][r]));
            pc.y = pk2(fast_tanh(ac[2][r]), fast_tanh(ac[3][r]));
            *reinterpret_cast<uint2*>(&ha[(q * 4 + r) * RS + 4 * c]) = pa;
            *reinterpret_cast<uint2*>(&hc[(q * 4 + r) * RS + 4 * c]) = pc;
        }

        // ---- layer 2 (bias via acc init) ----
        #pragma unroll
        for (int nt = 0; nt < 4; ++nt) {
            aa[nt] = f32x4{b2v[nt], b2v[nt], b2v[nt], b2v[nt]};
            ac[nt] = f32x4{bc2v[nt], bc2v[nt], bc2v[nt], bc2v[nt]};
        }
        #pragma unroll
        for (int kb = 0; kb < 2; ++kb) {
            bf8 xa = *reinterpret_cast<const bf8*>(&ha[c * RS + kb * 32 + q * 8]);
            bf8 xc = *reinterpret_cast<const bf8*>(&hc[c * RS + kb * 32 + q * 8]);
            #pragma unroll
            for (int nt = 0; nt < 4; ++nt) {
                aa[nt] = __builtin_amdgcn_mfma_f32_16x16x32_bf16(xa, fW2L [(kb * 4 + nt) * 64 + l], aa[nt], 0, 0, 0);
                ac[nt] = __builtin_amdgcn_mfma_f32_16x16x32_bf16(xc, fWc2L[(kb * 4 + nt) * 64 + l], ac[nt], 0, 0, 0);
            }
        }
        #pragma unroll
        for (int r = 0; r < 4; ++r) {
            uint2 pa, pc;
            pa.x = pk2(fast_tanh(aa[0][r]), fast_tanh(aa[1][r]));
            pa.y = pk2(fast_tanh(aa[2][r]), fast_tanh(aa[3][r]));
            pc.x = pk2(fast_tanh(ac[0][r]), fast_tanh(ac[1][r]));
            pc.y = pk2(fast_tanh(ac[2][r]), fast_tanh(ac[3][r]));
            *reinterpret_cast<uint2*>(&ha[(q * 4 + r) * RS + 4 * c]) = pa;
            *reinterpret_cast<uint2*>(&hc[(q * 4 + r) * RS + 4 * c]) = pc;
        }

        // ---- head: feat[16x64] @ [64x16] (cols 0-14 logits, col 15 value) ----
        {
            f32x4 lg = f32x4{bhv, bhv, bhv, bhv};
            f32x4 vv = f32x4{bhv, bhv, bhv, bhv};
            #pragma unroll
            for (int kb = 0; kb < 2; ++kb) {
                bf8 bw = fWhL[kb * 64 + l];
                bf8 fa = *reinterpret_cast<const bf8*>(&ha[c * RS + kb * 32 + q * 8]);
                bf8 fc = *reinterpret_cast<const bf8*>(&hc[c * RS + kb * 32 + q * 8]);
                lg = __builtin_amdgcn_mfma_f32_16x16x32_bf16(fa, bw, lg, 0, 0, 0);
                vv = __builtin_amdgcn_mfma_f32_16x16x32_bf16(fc, bw, vv, 0, 0, 0);
            }
            #pragma unroll
            for (int r = 0; r < 4; ++r)
                lw[(q * 4 + r) * LS + c] = f2bs(lg[r]);
            if (c == 15) {
                #pragma unroll
                for (int r = 0; r < 4; ++r)
                    vb[q * 4 + r] = vv[r];
            }
        }

        // ---- epilogue: lanes 0-15 of each wave (wave-local LDS, in-order DS pipe) ----
        if (l < 16) {
            float lg[5];
            #pragma unroll
            for (int a = 0; a < 5; ++a)
                lg[a] = bs2f(lw[c * LS + evc * 5 + a]);
            float mx = lg[0];
            #pragma unroll
            for (int a = 1; a < 5; ++a) mx = fmaxf(mx, lg[a]);
            float se = 0.f;
            #pragma unroll
            for (int a = 0; a < 5; ++a) se += __expf(lg[a] - mx);
            float lse = __logf(se) + mx;
            float lsel = lg[0];
            #pragma unroll
            for (int a = 1; a < 5; ++a) lsel = (act == a) ? lg[a] : lsel;
            float ent = 0.f;
            #pragma unroll
            for (int a = 0; a < 5; ++a) { float lp = lg[a] - lse; ent -= __expf(lp) * lp; }

            out[gm]          = (float)act;
            out[Bt + gm]     = lsel - lse;
            out[2 * Bt + gm] = ent;
            out[3 * Bt + gm] = vb[c];
        }

        // pack next iteration's fragments (raw loads have landed by now)
        if (i + 1 < ITERS) packaf();
    }
}

extern "C" void kernel_launch(void* const* d_in, const int* in_sizes, int n_in,
                              void* d_out, int out_size, void* d_ws, size_t ws_size,
                              hipStream_t stream) {
    const float* x   = (const float*)d_in[0];
    const int*   act = (const int*)  d_in[1];
    const float* W1  = (const float*)d_in[2];
    const float* b1  = (const float*)d_in[3];
    const float* W2  = (const float*)d_in[4];
    const float* b2  = (const float*)d_in[5];
    const float* Wh  = (const float*)d_in[6];
    const float* bh  = (const float*)d_in[7];
    const float* Wc1 = (const float*)d_in[8];
    const float* bc1 = (const float*)d_in[9];
    const float* Wc2 = (const float*)d_in[10];
    const float* bc2 = (const float*)d_in[11];
    const float* Wc3 = (const float*)d_in[12];
    const float* bc3 = (const float*)d_in[13];
    float* out = (float*)d_out;
    short* ws  = (short*)d_ws;

    hipLaunchKernelGGL(prep, dim3(32), dim3(256), 0, stream,
                       W1, b1, W2, Wh, Wc1, bc1, Wc2, Wc3, ws);
    hipLaunchKernelGGL(fused_ac, dim3(Bt / RPB), dim3(NT), 0, stream,
                       x, act, b2, bc2, bh, bc3, ws, out);
}